// Round 3
// baseline (1584.631 us; speedup 1.0000x reference)
//
#include <hip/hip_runtime.h>

#define NEG_SLOPE 0.2f

// ===========================================================================
// Fallback path (round-1): edge-parallel atomic scatter + shfl transform.
// ===========================================================================
__global__ void spmm_scatter_kernel(const float* __restrict__ emb,
                                    const int* __restrict__ row,
                                    const int* __restrict__ col,
                                    const float* __restrict__ val,
                                    float* __restrict__ acc,
                                    int n_edges) {
    const int lane = threadIdx.x & 63;
    const int waves_per_block = blockDim.x >> 6;
    const int wave_in_block = threadIdx.x >> 6;
    const int total_waves = gridDim.x * waves_per_block;
    for (int e = blockIdx.x * waves_per_block + wave_in_block; e < n_edges; e += total_waves) {
        const int r = row[e];
        const int c = col[e];
        const float v = val[e];
        const float m = v * emb[(size_t)c * 64 + lane];
        atomicAdd(&acc[(size_t)r * 64 + lane], m);
    }
}

__global__ void transform_leaky_kernel(float* __restrict__ io,
                                       const float* __restrict__ W_u,
                                       const float* __restrict__ W_i,
                                       int n_u_rows,
                                       int n_total_rows) {
    __shared__ float Ws[2][64 * 64];
    for (int i = threadIdx.x; i < 64 * 64; i += blockDim.x) {
        Ws[0][i] = W_u[i];
        Ws[1][i] = W_i[i];
    }
    __syncthreads();
    const int lane = threadIdx.x & 63;
    const int waves_per_block = blockDim.x >> 6;
    const int wave_in_block = threadIdx.x >> 6;
    const int total_waves = gridDim.x * waves_per_block;
    for (int r = blockIdx.x * waves_per_block + wave_in_block; r < n_total_rows; r += total_waves) {
        const float* W = (r < n_u_rows) ? Ws[0] : Ws[1];
        const float hv = io[(size_t)r * 64 + lane];
        float acc = 0.0f;
        #pragma unroll
        for (int k = 0; k < 64; ++k) {
            const float hk = __shfl(hv, k, 64);
            acc = fmaf(hk, W[k * 64 + lane], acc);
        }
        const float o = acc > 0.0f ? acc : NEG_SLOPE * acc;
        io[(size_t)r * 64 + lane] = o;
    }
}

// ===========================================================================
// CSR build: histogram -> exclusive scan (3 kernels) -> reorder (int2 edges)
// ===========================================================================
__global__ void hist_kernel(const int* __restrict__ rows, int n_edges, int row_off,
                            int* __restrict__ counts) {
    const int stride = gridDim.x * blockDim.x;
    for (int e = blockIdx.x * blockDim.x + threadIdx.x; e < n_edges; e += stride) {
        atomicAdd(&counts[row_off + rows[e]], 1);
    }
}

__global__ void scan_part1_kernel(const int* __restrict__ counts, int n,
                                  int* __restrict__ partials) {
    __shared__ int s[512];
    const int gi = blockIdx.x * 512 + threadIdx.x;
    s[threadIdx.x] = (gi < n) ? counts[gi] : 0;
    __syncthreads();
    for (int off = 256; off > 0; off >>= 1) {
        if (threadIdx.x < off) s[threadIdx.x] += s[threadIdx.x + off];
        __syncthreads();
    }
    if (threadIdx.x == 0) partials[blockIdx.x] = s[0];
}

__global__ void scan_part2_kernel(int* __restrict__ partials, int nb) {
    __shared__ int s[1024];
    const int tid = threadIdx.x;
    int v = (tid < nb) ? partials[tid] : 0;
    s[tid] = v;
    __syncthreads();
    for (int off = 1; off < 1024; off <<= 1) {
        int t = (tid >= off) ? s[tid - off] : 0;
        __syncthreads();
        s[tid] += t;
        __syncthreads();
    }
    if (tid < nb) partials[tid] = s[tid] - v;  // exclusive
}

__global__ void scan_part3_kernel(const int* __restrict__ counts, int n,
                                  const int* __restrict__ partials,
                                  int* __restrict__ row_ptr) {
    __shared__ int s[512];
    const int tid = threadIdx.x;
    const int gi = blockIdx.x * 512 + tid;
    const int v = (gi < n) ? counts[gi] : 0;
    s[tid] = v;
    __syncthreads();
    for (int off = 1; off < 512; off <<= 1) {
        int t = (tid >= off) ? s[tid - off] : 0;
        __syncthreads();
        s[tid] += t;
        __syncthreads();
    }
    const int base = partials[blockIdx.x];
    if (gi < n) {
        row_ptr[gi] = base + s[tid] - v;              // exclusive
        if (gi == n - 1) row_ptr[n] = base + s[tid];  // total
    }
}

// Uses row_ptr itself as the cursor: after this kernel row_ptr[r] equals the
// ORIGINAL exclusive prefix of r+1 (i.e. shifted by one). Gather reads
// start = row_ptr[r-1] (0 for r==0), end = row_ptr[r].
__global__ void reorder_kernel(const int* __restrict__ rows,
                               const int* __restrict__ cols,
                               const float* __restrict__ vals,
                               int n_edges, int row_off,
                               int* __restrict__ row_pos,
                               int2* __restrict__ csr_edge) {
    const int stride = gridDim.x * blockDim.x;
    for (int e = blockIdx.x * blockDim.x + threadIdx.x; e < n_edges; e += stride) {
        const int r = row_off + rows[e];
        const int pos = atomicAdd(&row_pos[r], 1);
        csr_edge[pos] = make_int2(cols[e], __float_as_int(vals[e]));
    }
}

// ===========================================================================
// Pre-transform: Y = emb @ W (fp32, no shfl). W columns live in 64 VGPRs per
// lane (lane = output dim). 128 rows staged in LDS via coalesced float4; the
// h-row is read with wave-uniform ds_read_b128 (broadcast, conflict-free).
// ===========================================================================
#define TROWS 128
__global__ void pretransform_kernel(const float* __restrict__ emb,
                                    const float* __restrict__ W,
                                    float* __restrict__ Y,
                                    int n_rows) {
    __shared__ float hs[TROWS * 64];  // 32 KB
    const int lane = threadIdx.x & 63;
    const int wid = threadIdx.x >> 6;

    float w[64];  // w[k] = W[k][lane]
    #pragma unroll
    for (int k = 0; k < 64; ++k) w[k] = W[k * 64 + lane];

    const int n_tiles = (n_rows + TROWS - 1) / TROWS;
    for (int tile = blockIdx.x; tile < n_tiles; tile += gridDim.x) {
        const int base = tile * TROWS;
        const int rows_here = min(TROWS, n_rows - base);

        __syncthreads();  // previous tile's readers done
        const float4* src = (const float4*)(emb + (size_t)base * 64);
        float4* dst = (float4*)hs;
        const int n4 = rows_here * 16;
        for (int i = threadIdx.x; i < n4; i += blockDim.x) dst[i] = src[i];
        __syncthreads();

        const int rpw = TROWS / 4;  // rows per wave
        const int rend = min((wid + 1) * rpw, rows_here);
        for (int rl = wid * rpw; rl < rend; ++rl) {
            float a0 = 0.f, a1 = 0.f, a2 = 0.f, a3 = 0.f;
            #pragma unroll
            for (int kq = 0; kq < 16; ++kq) {
                const float4 h = *(const float4*)(&hs[rl * 64 + kq * 4]);
                a0 = fmaf(h.x, w[kq * 4 + 0], a0);
                a1 = fmaf(h.y, w[kq * 4 + 1], a1);
                a2 = fmaf(h.z, w[kq * 4 + 2], a2);
                a3 = fmaf(h.w, w[kq * 4 + 3], a3);
            }
            Y[(size_t)(base + rl) * 64 + lane] = (a0 + a1) + (a2 + a3);
        }
    }
}

// ===========================================================================
// Gather + leaky: out[r] = leaky(sum_e val_e * Y[col_e]). One wave per row;
// edge descriptors are wave-uniform scalar loads (int2 -> s_load_dwordx2),
// the fma uses the SGPR operand slot for val. No cross-lane ops.
// ===========================================================================
__global__ void csr_gather_leaky_kernel(const float* __restrict__ Y,
                                        const int* __restrict__ row_pos,
                                        const int2* __restrict__ edges,
                                        float* __restrict__ out,
                                        int n_u, int n_rows) {
    const int lane = threadIdx.x & 63;
    const int wpb = blockDim.x >> 6;
    const int wib = threadIdx.x >> 6;
    const int total_waves = gridDim.x * wpb;

    for (int r0 = blockIdx.x * wpb + wib; r0 < n_rows; r0 += total_waves) {
        const int r = __builtin_amdgcn_readfirstlane(r0);
        const int start = (r == 0) ? 0 : row_pos[r - 1];
        const int end = row_pos[r];
        const float* __restrict__ base = (r < n_u) ? Y : (Y + (size_t)n_u * 64);

        float a0 = 0.f, a1 = 0.f;
        int j = start;
        for (; j + 4 <= end; j += 4) {
            const int2 e0 = edges[j];
            const int2 e1 = edges[j + 1];
            const int2 e2 = edges[j + 2];
            const int2 e3 = edges[j + 3];
            const float y0 = base[(size_t)e0.x * 64 + lane];
            const float y1 = base[(size_t)e1.x * 64 + lane];
            const float y2 = base[(size_t)e2.x * 64 + lane];
            const float y3 = base[(size_t)e3.x * 64 + lane];
            a0 = fmaf(__int_as_float(e0.y), y0, a0);
            a1 = fmaf(__int_as_float(e1.y), y1, a1);
            a0 = fmaf(__int_as_float(e2.y), y2, a0);
            a1 = fmaf(__int_as_float(e3.y), y3, a1);
        }
        for (; j < end; ++j) {
            const int2 e0 = edges[j];
            a0 = fmaf(__int_as_float(e0.y), base[(size_t)e0.x * 64 + lane], a0);
        }
        const float acc = a0 + a1;
        out[(size_t)r * 64 + lane] = acc > 0.f ? acc : NEG_SLOPE * acc;
    }
}

// ===========================================================================
extern "C" void kernel_launch(void* const* d_in, const int* in_sizes, int n_in,
                              void* d_out, int out_size, void* d_ws, size_t ws_size,
                              hipStream_t stream) {
    const float* users_emb = (const float*)d_in[0];
    const float* items_emb = (const float*)d_in[1];
    const int*   u_row     = (const int*)d_in[2];
    const int*   u_col     = (const int*)d_in[3];
    const float* u_val     = (const float*)d_in[4];
    const int*   i_row     = (const int*)d_in[5];
    const int*   i_col     = (const int*)d_in[6];
    const float* i_val     = (const float*)d_in[7];
    const float* W_u       = (const float*)d_in[8];
    const float* W_i       = (const float*)d_in[9];

    const int n_u = in_sizes[0] / 64;   // 100000
    const int n_i = in_sizes[1] / 64;   // 200000
    const int e_u = in_sizes[2];        // 1.6M
    const int e_i = in_sizes[5];        // 3.2M
    const int n_rows = n_u + n_i;       // 300000
    const long long E = (long long)e_u + e_i;  // 4.8M

    float* out = (float*)d_out;

    const int BLK = 256;
    const int WPB = BLK / 64;
    const int GRID_CAP = 2048;
    const int nb = (n_rows + 511) / 512;  // 586 <= 1024

    // Workspace layout (16B-aligned sections, word offsets):
    //   counts [n_rows] | row_ptr [n_rows+1] | partials [nb] |
    //   Y [n_rows*64] floats | csr_edge [E] int2
    size_t off = 0;
    const size_t o_counts = off;            off += (size_t)n_rows;       off = (off + 3) & ~(size_t)3;
    const size_t o_rowptr = off;            off += (size_t)n_rows + 1;   off = (off + 3) & ~(size_t)3;
    const size_t o_part   = off;            off += (size_t)nb;           off = (off + 3) & ~(size_t)3;
    const size_t o_Y      = off;            off += (size_t)n_rows * 64;  off = (off + 3) & ~(size_t)3;
    const size_t o_edge   = off;            off += (size_t)E * 2;
    const size_t need_bytes = off * 4;

    if (ws_size >= need_bytes && nb <= 1024) {
        int*   counts   = (int*)d_ws + o_counts;
        int*   row_ptr  = (int*)d_ws + o_rowptr;
        int*   partials = (int*)d_ws + o_part;
        float* Yw       = (float*)d_ws + o_Y;
        int2*  csr_edge = (int2*)((int*)d_ws + o_edge);

        // ---- pre-transform (independent of CSR build) ----
        const int tiles_u = (n_u + TROWS - 1) / TROWS;
        const int tiles_i = (n_i + TROWS - 1) / TROWS;
        pretransform_kernel<<<tiles_u, BLK, 0, stream>>>(users_emb, W_u, Yw, n_u);
        pretransform_kernel<<<tiles_i, BLK, 0, stream>>>(items_emb, W_i,
                                                         Yw + (size_t)n_u * 64, n_i);

        // ---- CSR build ----
        hipMemsetAsync(counts, 0, (size_t)n_rows * 4, stream);
        hist_kernel<<<GRID_CAP, BLK, 0, stream>>>(u_row, e_u, 0, counts);
        hist_kernel<<<GRID_CAP, BLK, 0, stream>>>(i_row, e_i, n_u, counts);
        scan_part1_kernel<<<nb, 512, 0, stream>>>(counts, n_rows, partials);
        scan_part2_kernel<<<1, 1024, 0, stream>>>(partials, nb);
        scan_part3_kernel<<<nb, 512, 0, stream>>>(counts, n_rows, partials, row_ptr);
        reorder_kernel<<<GRID_CAP, BLK, 0, stream>>>(u_row, u_col, u_val, e_u, 0,
                                                     row_ptr, csr_edge);
        reorder_kernel<<<GRID_CAP, BLK, 0, stream>>>(i_row, i_col, i_val, e_i, n_u,
                                                     row_ptr, csr_edge);

        // ---- gather + leaky (writes every output row) ----
        int grid_g = (n_rows + WPB - 1) / WPB;
        if (grid_g > GRID_CAP) grid_g = GRID_CAP;
        csr_gather_leaky_kernel<<<grid_g, BLK, 0, stream>>>(Yw, row_ptr, csr_edge,
                                                            out, n_u, n_rows);
    } else {
        // Fallback: atomic scatter + shfl transform (round-1 path)
        float* out_u = out;
        float* out_i = out + (size_t)n_u * 64;
        hipMemsetAsync(d_out, 0, (size_t)out_size * sizeof(float), stream);
        int grid_u = (e_u + WPB - 1) / WPB;
        int grid_i = (e_i + WPB - 1) / WPB;
        const int SCAP = 256 * 8;
        if (grid_u > SCAP) grid_u = SCAP;
        if (grid_i > SCAP) grid_i = SCAP;
        spmm_scatter_kernel<<<grid_u, BLK, 0, stream>>>(users_emb, u_row, u_col, u_val, out_u, e_u);
        spmm_scatter_kernel<<<grid_i, BLK, 0, stream>>>(items_emb, i_row, i_col, i_val, out_i, e_i);
        int grid_t = (n_rows + WPB - 1) / WPB;
        if (grid_t > GRID_CAP) grid_t = GRID_CAP;
        transform_leaky_kernel<<<grid_t, BLK, 0, stream>>>(out, W_u, W_i, n_u, n_rows);
    }
}

// Round 4
// 799.523 us; speedup vs baseline: 1.9820x; 1.9820x over previous
//
#include <hip/hip_runtime.h>

#define NEG_SLOPE 0.2f

// ===========================================================================
// Fallback path (round-1): edge-parallel atomic scatter + shfl transform.
// ===========================================================================
__global__ void spmm_scatter_kernel(const float* __restrict__ emb,
                                    const int* __restrict__ row,
                                    const int* __restrict__ col,
                                    const float* __restrict__ val,
                                    float* __restrict__ acc,
                                    int n_edges) {
    const int lane = threadIdx.x & 63;
    const int waves_per_block = blockDim.x >> 6;
    const int wave_in_block = threadIdx.x >> 6;
    const int total_waves = gridDim.x * waves_per_block;
    for (int e = blockIdx.x * waves_per_block + wave_in_block; e < n_edges; e += total_waves) {
        const int r = row[e];
        const int c = col[e];
        const float v = val[e];
        const float m = v * emb[(size_t)c * 64 + lane];
        atomicAdd(&acc[(size_t)r * 64 + lane], m);
    }
}

__global__ void transform_leaky_kernel(float* __restrict__ io,
                                       const float* __restrict__ W_u,
                                       const float* __restrict__ W_i,
                                       int n_u_rows,
                                       int n_total_rows) {
    __shared__ float Ws[2][64 * 64];
    for (int i = threadIdx.x; i < 64 * 64; i += blockDim.x) {
        Ws[0][i] = W_u[i];
        Ws[1][i] = W_i[i];
    }
    __syncthreads();
    const int lane = threadIdx.x & 63;
    const int waves_per_block = blockDim.x >> 6;
    const int wave_in_block = threadIdx.x >> 6;
    const int total_waves = gridDim.x * waves_per_block;
    for (int r = blockIdx.x * waves_per_block + wave_in_block; r < n_total_rows; r += total_waves) {
        const float* W = (r < n_u_rows) ? Ws[0] : Ws[1];
        const float hv = io[(size_t)r * 64 + lane];
        float acc = 0.0f;
        #pragma unroll
        for (int k = 0; k < 64; ++k) {
            const float hk = __shfl(hv, k, 64);
            acc = fmaf(hk, W[k * 64 + lane], acc);
        }
        const float o = acc > 0.0f ? acc : NEG_SLOPE * acc;
        io[(size_t)r * 64 + lane] = o;
    }
}

// ===========================================================================
// CSR build: histogram -> exclusive scan (3 kernels) -> reorder (int2 edges)
// ===========================================================================
__global__ void hist_kernel(const int* __restrict__ rows, int n_edges, int row_off,
                            int* __restrict__ counts) {
    const int stride = gridDim.x * blockDim.x;
    for (int e = blockIdx.x * blockDim.x + threadIdx.x; e < n_edges; e += stride) {
        atomicAdd(&counts[row_off + rows[e]], 1);
    }
}

__global__ void scan_part1_kernel(const int* __restrict__ counts, int n,
                                  int* __restrict__ partials) {
    __shared__ int s[512];
    const int gi = blockIdx.x * 512 + threadIdx.x;
    s[threadIdx.x] = (gi < n) ? counts[gi] : 0;
    __syncthreads();
    for (int off = 256; off > 0; off >>= 1) {
        if (threadIdx.x < off) s[threadIdx.x] += s[threadIdx.x + off];
        __syncthreads();
    }
    if (threadIdx.x == 0) partials[blockIdx.x] = s[0];
}

__global__ void scan_part2_kernel(int* __restrict__ partials, int nb) {
    __shared__ int s[1024];
    const int tid = threadIdx.x;
    int v = (tid < nb) ? partials[tid] : 0;
    s[tid] = v;
    __syncthreads();
    for (int off = 1; off < 1024; off <<= 1) {
        int t = (tid >= off) ? s[tid - off] : 0;
        __syncthreads();
        s[tid] += t;
        __syncthreads();
    }
    if (tid < nb) partials[tid] = s[tid] - v;  // exclusive
}

__global__ void scan_part3_kernel(const int* __restrict__ counts, int n,
                                  const int* __restrict__ partials,
                                  int* __restrict__ row_ptr) {
    __shared__ int s[512];
    const int tid = threadIdx.x;
    const int gi = blockIdx.x * 512 + tid;
    const int v = (gi < n) ? counts[gi] : 0;
    s[tid] = v;
    __syncthreads();
    for (int off = 1; off < 512; off <<= 1) {
        int t = (tid >= off) ? s[tid - off] : 0;
        __syncthreads();
        s[tid] += t;
        __syncthreads();
    }
    const int base = partials[blockIdx.x];
    if (gi < n) {
        row_ptr[gi] = base + s[tid] - v;              // exclusive
        if (gi == n - 1) row_ptr[n] = base + s[tid];  // total
    }
}

// Uses row_ptr itself as the cursor: after this kernel row_ptr[r] equals the
// ORIGINAL exclusive prefix of r+1 (i.e. shifted by one). Gather reads
// start = row_ptr[r-1] (0 for r==0), end = row_ptr[r].
__global__ void reorder_kernel(const int* __restrict__ rows,
                               const int* __restrict__ cols,
                               const float* __restrict__ vals,
                               int n_edges, int row_off,
                               int* __restrict__ row_pos,
                               int2* __restrict__ csr_edge) {
    const int stride = gridDim.x * blockDim.x;
    for (int e = blockIdx.x * blockDim.x + threadIdx.x; e < n_edges; e += stride) {
        const int r = row_off + rows[e];
        const int pos = atomicAdd(&row_pos[r], 1);
        csr_edge[pos] = make_int2(cols[e], __float_as_int(vals[e]));
    }
}

// ===========================================================================
// Pre-transform: Y = emb @ W (fp32). Both operands in LDS; per-thread state
// is just a float4 accumulator (no big register arrays -> no spill).
// Lane decomposition: rsub = lane>>4 (4 rows/wave), jg = lane&15 (4 out dims).
//   W reads:  Ws[k][4jg..4jg+3] -- 16 consecutive float4 per group, broadcast
//             across the 4 row groups -> conflict-free.
//   h reads:  hs[row][kq] with rows padded to 68 floats -> bank starts differ
//             by 4 per row -> conflict-free ds_read_b128.
// ===========================================================================
#define PT_ROWS 64
__global__ void pretransform_kernel(const float* __restrict__ emb,
                                    const float* __restrict__ W,
                                    float* __restrict__ Y,
                                    int n_rows) {
    __shared__ float Ws[64 * 64];       // 16 KB, W[k][j] row-major
    __shared__ float hs[PT_ROWS][68];   // 17.4 KB, padded rows

    const int lane = threadIdx.x & 63;
    const int wid  = threadIdx.x >> 6;   // 0..3
    const int rsub = lane >> 4;          // 0..3
    const int jg   = lane & 15;          // output dims 4*jg .. 4*jg+3

    // load W once (coalesced float4); ordered before use by the staging sync
    {
        const float4* src = (const float4*)W;
        float4* dst = (float4*)Ws;
        for (int i = threadIdx.x; i < 64 * 16; i += blockDim.x) dst[i] = src[i];
    }

    const int n_tiles = (n_rows + PT_ROWS - 1) / PT_ROWS;
    for (int tile = blockIdx.x; tile < n_tiles; tile += gridDim.x) {
        const int base = tile * PT_ROWS;
        const int rows_here = min(PT_ROWS, n_rows - base);

        __syncthreads();  // previous tile's readers done (also fences W load)
        for (int i = threadIdx.x; i < rows_here * 16; i += blockDim.x) {
            const int r = i >> 4, q = i & 15;
            const float4 v = ((const float4*)(emb + (size_t)(base + r) * 64))[q];
            *(float4*)&hs[r][q * 4] = v;
        }
        __syncthreads();

        // wave handles row-quads wid, wid+4, wid+8, wid+12
        #pragma unroll
        for (int quad = 0; quad < 4; ++quad) {
            const int r = (wid + quad * 4) * 4 + rsub;
            if (r < rows_here) {
                float ax = 0.f, ay = 0.f, az = 0.f, aw = 0.f;
                #pragma unroll
                for (int kq = 0; kq < 16; ++kq) {
                    const float4 h = *(const float4*)&hs[r][kq * 4];
                    const float4 w0 = *(const float4*)&Ws[(kq * 4 + 0) * 64 + jg * 4];
                    const float4 w1 = *(const float4*)&Ws[(kq * 4 + 1) * 64 + jg * 4];
                    const float4 w2 = *(const float4*)&Ws[(kq * 4 + 2) * 64 + jg * 4];
                    const float4 w3 = *(const float4*)&Ws[(kq * 4 + 3) * 64 + jg * 4];
                    ax = fmaf(h.x, w0.x, ax); ay = fmaf(h.x, w0.y, ay);
                    az = fmaf(h.x, w0.z, az); aw = fmaf(h.x, w0.w, aw);
                    ax = fmaf(h.y, w1.x, ax); ay = fmaf(h.y, w1.y, ay);
                    az = fmaf(h.y, w1.z, az); aw = fmaf(h.y, w1.w, aw);
                    ax = fmaf(h.z, w2.x, ax); ay = fmaf(h.z, w2.y, ay);
                    az = fmaf(h.z, w2.z, az); aw = fmaf(h.z, w2.w, aw);
                    ax = fmaf(h.w, w3.x, ax); ay = fmaf(h.w, w3.y, ay);
                    az = fmaf(h.w, w3.z, az); aw = fmaf(h.w, w3.w, aw);
                }
                float4 acc; acc.x = ax; acc.y = ay; acc.z = az; acc.w = aw;
                *(float4*)(Y + (size_t)(base + r) * 64 + jg * 4) = acc;
            }
        }
    }
}

// ===========================================================================
// Gather + leaky: out[r] = leaky(sum_e val_e * Y[col_e]). One wave per row;
// edge descriptors are wave-uniform loads; no cross-lane ops.
// ===========================================================================
__global__ void csr_gather_leaky_kernel(const float* __restrict__ Y,
                                        const int* __restrict__ row_pos,
                                        const int2* __restrict__ edges,
                                        float* __restrict__ out,
                                        int n_u, int n_rows) {
    const int lane = threadIdx.x & 63;
    const int wpb = blockDim.x >> 6;
    const int wib = threadIdx.x >> 6;
    const int total_waves = gridDim.x * wpb;

    for (int r0 = blockIdx.x * wpb + wib; r0 < n_rows; r0 += total_waves) {
        const int r = __builtin_amdgcn_readfirstlane(r0);
        const int start = (r == 0) ? 0 : row_pos[r - 1];
        const int end = row_pos[r];
        const float* __restrict__ base = (r < n_u) ? Y : (Y + (size_t)n_u * 64);

        float a0 = 0.f, a1 = 0.f;
        int j = start;
        for (; j + 4 <= end; j += 4) {
            const int2 e0 = edges[j];
            const int2 e1 = edges[j + 1];
            const int2 e2 = edges[j + 2];
            const int2 e3 = edges[j + 3];
            const float y0 = base[(size_t)e0.x * 64 + lane];
            const float y1 = base[(size_t)e1.x * 64 + lane];
            const float y2 = base[(size_t)e2.x * 64 + lane];
            const float y3 = base[(size_t)e3.x * 64 + lane];
            a0 = fmaf(__int_as_float(e0.y), y0, a0);
            a1 = fmaf(__int_as_float(e1.y), y1, a1);
            a0 = fmaf(__int_as_float(e2.y), y2, a0);
            a1 = fmaf(__int_as_float(e3.y), y3, a1);
        }
        for (; j < end; ++j) {
            const int2 e0 = edges[j];
            a0 = fmaf(__int_as_float(e0.y), base[(size_t)e0.x * 64 + lane], a0);
        }
        const float acc = a0 + a1;
        out[(size_t)r * 64 + lane] = acc > 0.f ? acc : NEG_SLOPE * acc;
    }
}

// ===========================================================================
extern "C" void kernel_launch(void* const* d_in, const int* in_sizes, int n_in,
                              void* d_out, int out_size, void* d_ws, size_t ws_size,
                              hipStream_t stream) {
    const float* users_emb = (const float*)d_in[0];
    const float* items_emb = (const float*)d_in[1];
    const int*   u_row     = (const int*)d_in[2];
    const int*   u_col     = (const int*)d_in[3];
    const float* u_val     = (const float*)d_in[4];
    const int*   i_row     = (const int*)d_in[5];
    const int*   i_col     = (const int*)d_in[6];
    const float* i_val     = (const float*)d_in[7];
    const float* W_u       = (const float*)d_in[8];
    const float* W_i       = (const float*)d_in[9];

    const int n_u = in_sizes[0] / 64;   // 100000
    const int n_i = in_sizes[1] / 64;   // 200000
    const int e_u = in_sizes[2];        // 1.6M
    const int e_i = in_sizes[5];        // 3.2M
    const int n_rows = n_u + n_i;       // 300000
    const long long E = (long long)e_u + e_i;  // 4.8M

    float* out = (float*)d_out;

    const int BLK = 256;
    const int WPB = BLK / 64;
    const int GRID_CAP = 2048;
    const int nb = (n_rows + 511) / 512;  // 586 <= 1024

    // Workspace layout (word offsets, 16B-aligned sections):
    //   counts [n_rows] | row_ptr [n_rows+1] | partials [nb] |
    //   Y [n_rows*64] floats | csr_edge [E] int2
    size_t off = 0;
    const size_t o_counts = off;            off += (size_t)n_rows;       off = (off + 3) & ~(size_t)3;
    const size_t o_rowptr = off;            off += (size_t)n_rows + 1;   off = (off + 3) & ~(size_t)3;
    const size_t o_part   = off;            off += (size_t)nb;           off = (off + 3) & ~(size_t)3;
    const size_t o_Y      = off;            off += (size_t)n_rows * 64;  off = (off + 3) & ~(size_t)3;
    const size_t o_edge   = off;            off += (size_t)E * 2;
    const size_t need_bytes = off * 4;

    if (ws_size >= need_bytes && nb <= 1024) {
        int*   counts   = (int*)d_ws + o_counts;
        int*   row_ptr  = (int*)d_ws + o_rowptr;
        int*   partials = (int*)d_ws + o_part;
        float* Yw       = (float*)d_ws + o_Y;
        int2*  csr_edge = (int2*)((int*)d_ws + o_edge);

        // ---- pre-transform (independent of CSR build) ----
        const int tiles_u = (n_u + PT_ROWS - 1) / PT_ROWS;
        const int tiles_i = (n_i + PT_ROWS - 1) / PT_ROWS;
        const int PT_CAP = 1024;  // LDS-limited to ~4 blocks/CU
        const int g_u = tiles_u < PT_CAP ? tiles_u : PT_CAP;
        const int g_i = tiles_i < PT_CAP ? tiles_i : PT_CAP;
        pretransform_kernel<<<g_u, BLK, 0, stream>>>(users_emb, W_u, Yw, n_u);
        pretransform_kernel<<<g_i, BLK, 0, stream>>>(items_emb, W_i,
                                                     Yw + (size_t)n_u * 64, n_i);

        // ---- CSR build ----
        hipMemsetAsync(counts, 0, (size_t)n_rows * 4, stream);
        hist_kernel<<<GRID_CAP, BLK, 0, stream>>>(u_row, e_u, 0, counts);
        hist_kernel<<<GRID_CAP, BLK, 0, stream>>>(i_row, e_i, n_u, counts);
        scan_part1_kernel<<<nb, 512, 0, stream>>>(counts, n_rows, partials);
        scan_part2_kernel<<<1, 1024, 0, stream>>>(partials, nb);
        scan_part3_kernel<<<nb, 512, 0, stream>>>(counts, n_rows, partials, row_ptr);
        reorder_kernel<<<GRID_CAP, BLK, 0, stream>>>(u_row, u_col, u_val, e_u, 0,
                                                     row_ptr, csr_edge);
        reorder_kernel<<<GRID_CAP, BLK, 0, stream>>>(i_row, i_col, i_val, e_i, n_u,
                                                     row_ptr, csr_edge);

        // ---- gather + leaky (writes every output row) ----
        int grid_g = (n_rows + WPB - 1) / WPB;
        if (grid_g > GRID_CAP) grid_g = GRID_CAP;
        csr_gather_leaky_kernel<<<grid_g, BLK, 0, stream>>>(Yw, row_ptr, csr_edge,
                                                            out, n_u, n_rows);
    } else {
        // Fallback: atomic scatter + shfl transform (round-1 path)
        float* out_u = out;
        float* out_i = out + (size_t)n_u * 64;
        hipMemsetAsync(d_out, 0, (size_t)out_size * sizeof(float), stream);
        int grid_u = (e_u + WPB - 1) / WPB;
        int grid_i = (e_i + WPB - 1) / WPB;
        const int SCAP = 256 * 8;
        if (grid_u > SCAP) grid_u = SCAP;
        if (grid_i > SCAP) grid_i = SCAP;
        spmm_scatter_kernel<<<grid_u, BLK, 0, stream>>>(users_emb, u_row, u_col, u_val, out_u, e_u);
        spmm_scatter_kernel<<<grid_i, BLK, 0, stream>>>(items_emb, i_row, i_col, i_val, out_i, e_i);
        int grid_t = (n_rows + WPB - 1) / WPB;
        if (grid_t > GRID_CAP) grid_t = GRID_CAP;
        transform_leaky_kernel<<<grid_t, BLK, 0, stream>>>(out, W_u, W_i, n_u, n_rows);
    }
}

// Round 5
// 798.037 us; speedup vs baseline: 1.9857x; 1.0019x over previous
//
#include <hip/hip_runtime.h>

#define NEG_SLOPE 0.2f

typedef unsigned int uint32;
typedef unsigned short ushort16;

__device__ __forceinline__ unsigned short f32_to_bf16_rne(float f) {
    uint32 u = __float_as_uint(f);
    u = (u + 0x7FFFu + ((u >> 16) & 1u)) >> 16;
    return (unsigned short)u;
}
__device__ __forceinline__ float bf16_to_f32(unsigned short b) {
    return __uint_as_float(((uint32)b) << 16);
}

// ===========================================================================
// Fallback path (round-1): edge-parallel atomic scatter + shfl transform.
// ===========================================================================
__global__ void spmm_scatter_kernel(const float* __restrict__ emb,
                                    const int* __restrict__ row,
                                    const int* __restrict__ col,
                                    const float* __restrict__ val,
                                    float* __restrict__ acc,
                                    int n_edges) {
    const int lane = threadIdx.x & 63;
    const int waves_per_block = blockDim.x >> 6;
    const int wave_in_block = threadIdx.x >> 6;
    const int total_waves = gridDim.x * waves_per_block;
    for (int e = blockIdx.x * waves_per_block + wave_in_block; e < n_edges; e += total_waves) {
        const int r = row[e];
        const int c = col[e];
        const float v = val[e];
        const float m = v * emb[(size_t)c * 64 + lane];
        atomicAdd(&acc[(size_t)r * 64 + lane], m);
    }
}

__global__ void transform_leaky_kernel(float* __restrict__ io,
                                       const float* __restrict__ W_u,
                                       const float* __restrict__ W_i,
                                       int n_u_rows,
                                       int n_total_rows) {
    __shared__ float Ws[2][64 * 64];
    for (int i = threadIdx.x; i < 64 * 64; i += blockDim.x) {
        Ws[0][i] = W_u[i];
        Ws[1][i] = W_i[i];
    }
    __syncthreads();
    const int lane = threadIdx.x & 63;
    const int waves_per_block = blockDim.x >> 6;
    const int wave_in_block = threadIdx.x >> 6;
    const int total_waves = gridDim.x * waves_per_block;
    for (int r = blockIdx.x * waves_per_block + wave_in_block; r < n_total_rows; r += total_waves) {
        const float* W = (r < n_u_rows) ? Ws[0] : Ws[1];
        const float hv = io[(size_t)r * 64 + lane];
        float acc = 0.0f;
        #pragma unroll
        for (int k = 0; k < 64; ++k) {
            const float hk = __shfl(hv, k, 64);
            acc = fmaf(hk, W[k * 64 + lane], acc);
        }
        const float o = acc > 0.0f ? acc : NEG_SLOPE * acc;
        io[(size_t)r * 64 + lane] = o;
    }
}

// ===========================================================================
// CSR build: batched histogram -> exclusive scan (3 kernels) -> batched
// reorder (int2 edges). Batching = 4 edges/thread via int4/float4 loads so
// the 4 atomics (and 4 scattered stores) are independent, not chained.
// ===========================================================================
__global__ void hist_batched_kernel(const int* __restrict__ rows, int n_edges,
                                    int row_off, int* __restrict__ counts) {
    const int tid = blockIdx.x * blockDim.x + threadIdx.x;
    const int stride = gridDim.x * blockDim.x;
    const int n4 = n_edges >> 2;
    for (int g = tid; g < n4; g += stride) {
        const int4 r4 = ((const int4*)rows)[g];
        atomicAdd(&counts[row_off + r4.x], 1);
        atomicAdd(&counts[row_off + r4.y], 1);
        atomicAdd(&counts[row_off + r4.z], 1);
        atomicAdd(&counts[row_off + r4.w], 1);
    }
    for (int e = (n4 << 2) + tid; e < n_edges; e += stride) {
        atomicAdd(&counts[row_off + rows[e]], 1);
    }
}

__global__ void scan_part1_kernel(const int* __restrict__ counts, int n,
                                  int* __restrict__ partials) {
    __shared__ int s[512];
    const int gi = blockIdx.x * 512 + threadIdx.x;
    s[threadIdx.x] = (gi < n) ? counts[gi] : 0;
    __syncthreads();
    for (int off = 256; off > 0; off >>= 1) {
        if (threadIdx.x < off) s[threadIdx.x] += s[threadIdx.x + off];
        __syncthreads();
    }
    if (threadIdx.x == 0) partials[blockIdx.x] = s[0];
}

__global__ void scan_part2_kernel(int* __restrict__ partials, int nb) {
    __shared__ int s[1024];
    const int tid = threadIdx.x;
    int v = (tid < nb) ? partials[tid] : 0;
    s[tid] = v;
    __syncthreads();
    for (int off = 1; off < 1024; off <<= 1) {
        int t = (tid >= off) ? s[tid - off] : 0;
        __syncthreads();
        s[tid] += t;
        __syncthreads();
    }
    if (tid < nb) partials[tid] = s[tid] - v;  // exclusive
}

__global__ void scan_part3_kernel(const int* __restrict__ counts, int n,
                                  const int* __restrict__ partials,
                                  int* __restrict__ row_ptr) {
    __shared__ int s[512];
    const int tid = threadIdx.x;
    const int gi = blockIdx.x * 512 + tid;
    const int v = (gi < n) ? counts[gi] : 0;
    s[tid] = v;
    __syncthreads();
    for (int off = 1; off < 512; off <<= 1) {
        int t = (tid >= off) ? s[tid - off] : 0;
        __syncthreads();
        s[tid] += t;
        __syncthreads();
    }
    const int base = partials[blockIdx.x];
    if (gi < n) {
        row_ptr[gi] = base + s[tid] - v;              // exclusive
        if (gi == n - 1) row_ptr[n] = base + s[tid];  // total
    }
}

// Uses row_ptr itself as the cursor: after this kernel row_pos[r] equals the
// ORIGINAL exclusive prefix of r+1 (shifted by one). Gather reads
// start = row_pos[r-1] (0 for r==0), end = row_pos[r].
__global__ void reorder_batched_kernel(const int* __restrict__ rows,
                                       const int* __restrict__ cols,
                                       const float* __restrict__ vals,
                                       int n_edges, int row_off,
                                       int* __restrict__ row_pos,
                                       int2* __restrict__ csr_edge) {
    const int tid = blockIdx.x * blockDim.x + threadIdx.x;
    const int stride = gridDim.x * blockDim.x;
    const int n4 = n_edges >> 2;
    for (int g = tid; g < n4; g += stride) {
        const int4 r4 = ((const int4*)rows)[g];
        const int4 c4 = ((const int4*)cols)[g];
        const float4 v4 = ((const float4*)vals)[g];
        const int p0 = atomicAdd(&row_pos[row_off + r4.x], 1);
        const int p1 = atomicAdd(&row_pos[row_off + r4.y], 1);
        const int p2 = atomicAdd(&row_pos[row_off + r4.z], 1);
        const int p3 = atomicAdd(&row_pos[row_off + r4.w], 1);
        csr_edge[p0] = make_int2(c4.x, __float_as_int(v4.x));
        csr_edge[p1] = make_int2(c4.y, __float_as_int(v4.y));
        csr_edge[p2] = make_int2(c4.z, __float_as_int(v4.z));
        csr_edge[p3] = make_int2(c4.w, __float_as_int(v4.w));
    }
    for (int e = (n4 << 2) + tid; e < n_edges; e += stride) {
        const int pos = atomicAdd(&row_pos[row_off + rows[e]], 1);
        csr_edge[pos] = make_int2(cols[e], __float_as_int(vals[e]));
    }
}

// ===========================================================================
// Pre-transform (fused u+i): Y = emb @ W, output bf16. Both operands in LDS;
// per-thread state is one float4 accumulator. One tile (64 rows) per block.
// Lane decomposition: rsub = lane>>4 (4 rows), jg = lane&15 (4 out dims).
// ===========================================================================
#define PT_ROWS 64
__global__ void pretransform_both_kernel(const float* __restrict__ uemb,
                                         const float* __restrict__ iemb,
                                         const float* __restrict__ W_u,
                                         const float* __restrict__ W_i,
                                         unsigned short* __restrict__ Ybf,
                                         int n_u, int n_i, int tiles_u) {
    __shared__ float Ws[64 * 64];       // 16 KB
    __shared__ float hs[PT_ROWS][68];   // 17.4 KB (padded rows)

    const int tile = blockIdx.x;
    const bool is_u = tile < tiles_u;
    const float* __restrict__ emb = is_u ? uemb : iemb;
    const float* __restrict__ W = is_u ? W_u : W_i;
    const int lt = is_u ? tile : tile - tiles_u;       // local tile
    const int nr = is_u ? n_u : n_i;
    const int base = lt * PT_ROWS;
    const int rows_here = min(PT_ROWS, nr - base);
    const size_t ybase = (is_u ? (size_t)base : (size_t)n_u + base) * 64;

    const int lane = threadIdx.x & 63;
    const int wid  = threadIdx.x >> 6;   // 0..3
    const int rsub = lane >> 4;          // 0..3
    const int jg   = lane & 15;          // output dims 4*jg .. 4*jg+3

    {
        const float4* src = (const float4*)W;
        float4* dst = (float4*)Ws;
        for (int i = threadIdx.x; i < 64 * 16; i += blockDim.x) dst[i] = src[i];
    }
    for (int i = threadIdx.x; i < rows_here * 16; i += blockDim.x) {
        const int r = i >> 4, q = i & 15;
        const float4 v = ((const float4*)(emb + (size_t)(base + r) * 64))[q];
        *(float4*)&hs[r][q * 4] = v;
    }
    __syncthreads();

    #pragma unroll
    for (int quad = 0; quad < 4; ++quad) {
        const int r = (wid + quad * 4) * 4 + rsub;
        if (r < rows_here) {
            float ax = 0.f, ay = 0.f, az = 0.f, aw = 0.f;
            #pragma unroll
            for (int kq = 0; kq < 16; ++kq) {
                const float4 h = *(const float4*)&hs[r][kq * 4];
                const float4 w0 = *(const float4*)&Ws[(kq * 4 + 0) * 64 + jg * 4];
                const float4 w1 = *(const float4*)&Ws[(kq * 4 + 1) * 64 + jg * 4];
                const float4 w2 = *(const float4*)&Ws[(kq * 4 + 2) * 64 + jg * 4];
                const float4 w3 = *(const float4*)&Ws[(kq * 4 + 3) * 64 + jg * 4];
                ax = fmaf(h.x, w0.x, ax); ay = fmaf(h.x, w0.y, ay);
                az = fmaf(h.x, w0.z, az); aw = fmaf(h.x, w0.w, aw);
                ax = fmaf(h.y, w1.x, ax); ay = fmaf(h.y, w1.y, ay);
                az = fmaf(h.y, w1.z, az); aw = fmaf(h.y, w1.w, aw);
                ax = fmaf(h.z, w2.x, ax); ay = fmaf(h.z, w2.y, ay);
                az = fmaf(h.z, w2.z, az); aw = fmaf(h.z, w2.w, aw);
                ax = fmaf(h.w, w3.x, ax); ay = fmaf(h.w, w3.y, ay);
                az = fmaf(h.w, w3.z, az); aw = fmaf(h.w, w3.w, aw);
            }
            ushort4 o;
            o.x = f32_to_bf16_rne(ax);
            o.y = f32_to_bf16_rne(ay);
            o.z = f32_to_bf16_rne(az);
            o.w = f32_to_bf16_rne(aw);
            *(ushort4*)(Ybf + ybase + (size_t)r * 64 + jg * 4) = o;
        }
    }
}

// ===========================================================================
// Gather + leaky: out[r] = leaky(sum_e val_e * Y[col_e]), Y in bf16 (128B/row
// gather segments). One wave per row; edge descriptors are wave-uniform.
// ===========================================================================
__global__ void csr_gather_leaky_kernel(const unsigned short* __restrict__ Ybf,
                                        const int* __restrict__ row_pos,
                                        const int2* __restrict__ edges,
                                        float* __restrict__ out,
                                        int n_u, int n_rows) {
    const int lane = threadIdx.x & 63;
    const int wpb = blockDim.x >> 6;
    const int wib = threadIdx.x >> 6;
    const int total_waves = gridDim.x * wpb;

    for (int r0 = blockIdx.x * wpb + wib; r0 < n_rows; r0 += total_waves) {
        const int r = __builtin_amdgcn_readfirstlane(r0);
        const int start = (r == 0) ? 0 : row_pos[r - 1];
        const int end = row_pos[r];
        const unsigned short* __restrict__ base =
            (r < n_u) ? Ybf : (Ybf + (size_t)n_u * 64);

        float a0 = 0.f, a1 = 0.f, a2 = 0.f, a3 = 0.f;
        int j = start;
        for (; j + 4 <= end; j += 4) {
            const int2 e0 = edges[j];
            const int2 e1 = edges[j + 1];
            const int2 e2 = edges[j + 2];
            const int2 e3 = edges[j + 3];
            const float y0 = bf16_to_f32(base[(size_t)e0.x * 64 + lane]);
            const float y1 = bf16_to_f32(base[(size_t)e1.x * 64 + lane]);
            const float y2 = bf16_to_f32(base[(size_t)e2.x * 64 + lane]);
            const float y3 = bf16_to_f32(base[(size_t)e3.x * 64 + lane]);
            a0 = fmaf(__int_as_float(e0.y), y0, a0);
            a1 = fmaf(__int_as_float(e1.y), y1, a1);
            a2 = fmaf(__int_as_float(e2.y), y2, a2);
            a3 = fmaf(__int_as_float(e3.y), y3, a3);
        }
        for (; j < end; ++j) {
            const int2 e0 = edges[j];
            a0 = fmaf(__int_as_float(e0.y), bf16_to_f32(base[(size_t)e0.x * 64 + lane]), a0);
        }
        const float acc = (a0 + a1) + (a2 + a3);
        out[(size_t)r * 64 + lane] = acc > 0.f ? acc : NEG_SLOPE * acc;
    }
}

// ===========================================================================
extern "C" void kernel_launch(void* const* d_in, const int* in_sizes, int n_in,
                              void* d_out, int out_size, void* d_ws, size_t ws_size,
                              hipStream_t stream) {
    const float* users_emb = (const float*)d_in[0];
    const float* items_emb = (const float*)d_in[1];
    const int*   u_row     = (const int*)d_in[2];
    const int*   u_col     = (const int*)d_in[3];
    const float* u_val     = (const float*)d_in[4];
    const int*   i_row     = (const int*)d_in[5];
    const int*   i_col     = (const int*)d_in[6];
    const float* i_val     = (const float*)d_in[7];
    const float* W_u       = (const float*)d_in[8];
    const float* W_i       = (const float*)d_in[9];

    const int n_u = in_sizes[0] / 64;   // 100000
    const int n_i = in_sizes[1] / 64;   // 200000
    const int e_u = in_sizes[2];        // 1.6M
    const int e_i = in_sizes[5];        // 3.2M
    const int n_rows = n_u + n_i;       // 300000
    const long long E = (long long)e_u + e_i;  // 4.8M

    float* out = (float*)d_out;

    const int BLK = 256;
    const int WPB = BLK / 64;
    const int GRID_CAP = 2048;
    const int nb = (n_rows + 511) / 512;  // 586 <= 1024

    // Workspace layout (word offsets, 16B-aligned sections):
    //   counts [n_rows] | row_ptr [n_rows+1] | partials [nb] |
    //   Ybf [n_rows*64] bf16 (= n_rows*32 words) | csr_edge [E] int2
    size_t off = 0;
    const size_t o_counts = off;  off += (size_t)n_rows;       off = (off + 3) & ~(size_t)3;
    const size_t o_rowptr = off;  off += (size_t)n_rows + 1;   off = (off + 3) & ~(size_t)3;
    const size_t o_part   = off;  off += (size_t)nb;           off = (off + 3) & ~(size_t)3;
    const size_t o_Y      = off;  off += (size_t)n_rows * 32;  off = (off + 3) & ~(size_t)3;
    const size_t o_edge   = off;  off += (size_t)E * 2;
    const size_t need_bytes = off * 4;

    if (ws_size >= need_bytes && nb <= 1024) {
        int*            counts   = (int*)d_ws + o_counts;
        int*            row_ptr  = (int*)d_ws + o_rowptr;
        int*            partials = (int*)d_ws + o_part;
        unsigned short* Ybf      = (unsigned short*)((int*)d_ws + o_Y);
        int2*           csr_edge = (int2*)((int*)d_ws + o_edge);

        // ---- pre-transform (fused u+i, one tile per block) ----
        const int tiles_u = (n_u + PT_ROWS - 1) / PT_ROWS;
        const int tiles_i = (n_i + PT_ROWS - 1) / PT_ROWS;
        pretransform_both_kernel<<<tiles_u + tiles_i, BLK, 0, stream>>>(
            users_emb, items_emb, W_u, W_i, Ybf, n_u, n_i, tiles_u);

        // ---- CSR build ----
        hipMemsetAsync(counts, 0, (size_t)n_rows * 4, stream);
        hist_batched_kernel<<<GRID_CAP, BLK, 0, stream>>>(u_row, e_u, 0, counts);
        hist_batched_kernel<<<GRID_CAP, BLK, 0, stream>>>(i_row, e_i, n_u, counts);
        scan_part1_kernel<<<nb, 512, 0, stream>>>(counts, n_rows, partials);
        scan_part2_kernel<<<1, 1024, 0, stream>>>(partials, nb);
        scan_part3_kernel<<<nb, 512, 0, stream>>>(counts, n_rows, partials, row_ptr);
        reorder_batched_kernel<<<GRID_CAP, BLK, 0, stream>>>(u_row, u_col, u_val, e_u, 0,
                                                             row_ptr, csr_edge);
        reorder_batched_kernel<<<GRID_CAP, BLK, 0, stream>>>(i_row, i_col, i_val, e_i, n_u,
                                                             row_ptr, csr_edge);

        // ---- gather + leaky (writes every output row) ----
        int grid_g = (n_rows + WPB - 1) / WPB;
        if (grid_g > GRID_CAP) grid_g = GRID_CAP;
        csr_gather_leaky_kernel<<<grid_g, BLK, 0, stream>>>(Ybf, row_ptr, csr_edge,
                                                            out, n_u, n_rows);
    } else {
        // Fallback: atomic scatter + shfl transform (round-1 path, fp32)
        float* out_u = out;
        float* out_i = out + (size_t)n_u * 64;
        hipMemsetAsync(d_out, 0, (size_t)out_size * sizeof(float), stream);
        int grid_u = (e_u + WPB - 1) / WPB;
        int grid_i = (e_i + WPB - 1) / WPB;
        const int SCAP = 256 * 8;
        if (grid_u > SCAP) grid_u = SCAP;
        if (grid_i > SCAP) grid_i = SCAP;
        spmm_scatter_kernel<<<grid_u, BLK, 0, stream>>>(users_emb, u_row, u_col, u_val, out_u, e_u);
        spmm_scatter_kernel<<<grid_i, BLK, 0, stream>>>(items_emb, i_row, i_col, i_val, out_i, e_i);
        int grid_t = (n_rows + WPB - 1) / WPB;
        if (grid_t > GRID_CAP) grid_t = GRID_CAP;
        transform_leaky_kernel<<<grid_t, BLK, 0, stream>>>(out, W_u, W_i, n_u, n_rows);
    }
}